// Round 2
// baseline (163.889 us; speedup 1.0000x reference)
//
#include <hip/hip_runtime.h>

// RoIAlign forward, torchvision semantics (aligned=false), fp32.
// N=2, C=256, H=200, W=200, K=1000 rois, pooled 7x7, sampling_ratio=2.
constexpr int Nn = 2, Cc = 256, Hh = 200, Ww = 200, Kk = 1000;
constexpr int PH = 7, PW = 7, SR = 2;
constexpr float SCALE = 0.25f;
constexpr int HWsz = Hh * Ww;

// ---------------------------------------------------------------------------
// NCHW -> NHWC transpose. Per batch: transpose a C x HW matrix to HW x C.
// 64x64 tiles staged through LDS; both global read and write coalesced.
// ---------------------------------------------------------------------------
__global__ __launch_bounds__(256) void transpose_nchw_nhwc(
    const float* __restrict__ in, float* __restrict__ out) {
  __shared__ float tile[64][65];  // +1 pad: conflict-free on both phases
  const int hw0 = blockIdx.x * 64;
  const int c0  = blockIdx.y * 64;
  const int b   = blockIdx.z;
  const int lane = threadIdx.x & 63;
  const int row  = threadIdx.x >> 6;  // 0..3

#pragma unroll
  for (int i = 0; i < 16; ++i) {
    const int cc = row + i * 4;
    tile[cc][lane] = in[(size_t)(b * Cc + c0 + cc) * HWsz + hw0 + lane];
  }
  __syncthreads();
#pragma unroll
  for (int i = 0; i < 16; ++i) {
    const int hh = row + i * 4;
    out[((size_t)b * HWsz + hw0 + hh) * Cc + c0 + lane] = tile[lane][hh];
  }
}

// ---------------------------------------------------------------------------
// RoI align on NHWC. One block per roi, 448 threads = 7 waves.
// wave (threadIdx>>6) = pooled row ph; lane = channel quad (float4 loads:
// each bilinear-neighbor gather is a contiguous 1KB read across the wave).
// Output staged through LDS in two 128-channel phases, then written with
// fully-coalesced linear stores (kills the 2x HBM write amplification).
// ---------------------------------------------------------------------------
__global__ __launch_bounds__(448, 7) void roi_align_nhwc(
    const float* __restrict__ feat, const float* __restrict__ rois,
    float* __restrict__ out) {
  __shared__ float stage[128 * PH * PW];  // 25088 B

  const int k    = blockIdx.x;
  const int ph   = (int)(threadIdx.x >> 6);   // 0..6
  const int lane = (int)(threadIdx.x & 63);

  const float* r = rois + k * 5;
  const int b = (int)r[0];
  const float x1 = r[1] * SCALE;
  const float y1 = r[2] * SCALE;
  const float x2 = r[3] * SCALE;
  const float y2 = r[4] * SCALE;
  const float bin_w = fmaxf(x2 - x1, 1.0f) * (1.0f / PW);
  const float bin_h = fmaxf(y2 - y1, 1.0f) * (1.0f / PH);

  // float4 index: (y*W + x)*64 + lane, relative to batch base.
  const float4* fb = (const float4*)feat + (size_t)b * (size_t)(HWsz * (Cc / 4)) + lane;

  float4 acc[PW];
#pragma unroll
  for (int i = 0; i < PW; ++i) acc[i] = make_float4(0.f, 0.f, 0.f, 0.f);

#pragma unroll
  for (int iy = 0; iy < SR; ++iy) {
    const float y  = y1 + ((float)ph + ((float)iy + 0.5f) * 0.5f) * bin_h;
    const bool vy  = (y >= -1.0f) && (y <= (float)Hh);
    const float cy = fmaxf(y, 0.0f);
    int yl = (int)cy;  // cy >= 0 so trunc == floor
    int yh;
    float fy;
    if (yl >= Hh - 1) { yl = Hh - 1; yh = Hh - 1; fy = 0.0f; }
    else              { yh = yl + 1; fy = cy - (float)yl; }
    float wyl = 1.0f - fy, wyh = fy;
    if (!vy) { wyl = 0.0f; wyh = 0.0f; }  // masked, branchless gathers below
    const int ylb = yl * Ww, yhb = yh * Ww;

#pragma unroll
    for (int pw = 0; pw < PW; ++pw) {
#pragma unroll
      for (int ix = 0; ix < SR; ++ix) {
        const float x  = x1 + ((float)pw + ((float)ix + 0.5f) * 0.5f) * bin_w;
        const bool vx  = (x >= -1.0f) && (x <= (float)Ww);
        const float cx = fmaxf(x, 0.0f);
        int xl = (int)cx;
        int xh;
        float fx;
        if (xl >= Ww - 1) { xl = Ww - 1; xh = Ww - 1; fx = 0.0f; }
        else              { xh = xl + 1; fx = cx - (float)xl; }
        float wxl = 1.0f - fx, wxh = fx;
        if (!vx) { wxl = 0.0f; wxh = 0.0f; }

        const float w00 = wyl * wxl, w01 = wyl * wxh;
        const float w10 = wyh * wxl, w11 = wyh * wxh;

        const float4 v00 = fb[(ylb + xl) * 64];
        const float4 v01 = fb[(ylb + xh) * 64];
        const float4 v10 = fb[(yhb + xl) * 64];
        const float4 v11 = fb[(yhb + xh) * 64];

        acc[pw].x = fmaf(w00, v00.x, fmaf(w01, v01.x, fmaf(w10, v10.x, fmaf(w11, v11.x, acc[pw].x))));
        acc[pw].y = fmaf(w00, v00.y, fmaf(w01, v01.y, fmaf(w10, v10.y, fmaf(w11, v11.y, acc[pw].y))));
        acc[pw].z = fmaf(w00, v00.z, fmaf(w01, v01.z, fmaf(w10, v10.z, fmaf(w11, v11.z, acc[pw].z))));
        acc[pw].w = fmaf(w00, v00.w, fmaf(w01, v01.w, fmaf(w10, v10.w, fmaf(w11, v11.w, acc[pw].w))));
      }
    }
  }

  const float inv = 1.0f / (SR * SR);
  const size_t obase = (size_t)k * (Cc * PH * PW);

  // Phase A: channels [0,128) -> LDS -> coalesced store.
  if (lane < 32) {
    const int c0 = lane * 4;
#pragma unroll
    for (int pw = 0; pw < PW; ++pw) {
      const int p = ph * PW + pw;
      stage[(c0 + 0) * 49 + p] = acc[pw].x * inv;
      stage[(c0 + 1) * 49 + p] = acc[pw].y * inv;
      stage[(c0 + 2) * 49 + p] = acc[pw].z * inv;
      stage[(c0 + 3) * 49 + p] = acc[pw].w * inv;
    }
  }
  __syncthreads();
#pragma unroll
  for (int i = 0; i < 14; ++i) {  // 128*49 = 6272 = 448*14
    const int idx = i * 448 + (int)threadIdx.x;
    out[obase + idx] = stage[idx];
  }
  __syncthreads();

  // Phase B: channels [128,256).
  if (lane >= 32) {
    const int c0 = (lane - 32) * 4;
#pragma unroll
    for (int pw = 0; pw < PW; ++pw) {
      const int p = ph * PW + pw;
      stage[(c0 + 0) * 49 + p] = acc[pw].x * inv;
      stage[(c0 + 1) * 49 + p] = acc[pw].y * inv;
      stage[(c0 + 2) * 49 + p] = acc[pw].z * inv;
      stage[(c0 + 3) * 49 + p] = acc[pw].w * inv;
    }
  }
  __syncthreads();
#pragma unroll
  for (int i = 0; i < 14; ++i) {
    const int idx = i * 448 + (int)threadIdx.x;
    out[obase + 6272 + idx] = stage[idx];
  }
}

extern "C" void kernel_launch(void* const* d_in, const int* in_sizes, int n_in,
                              void* d_out, int out_size, void* d_ws, size_t ws_size,
                              hipStream_t stream) {
  const float* inp  = (const float*)d_in[0];   // (2,256,200,200) fp32
  const float* rois = (const float*)d_in[1];   // (1000,5) fp32
  float* out = (float*)d_out;                  // (1000,256,7,7) fp32

  float* nhwc = (float*)d_ws;                  // 164 MB, ws is large enough
  transpose_nchw_nhwc<<<dim3(HWsz / 64, Cc / 64, Nn), 256, 0, stream>>>(inp, nhwc);
  roi_align_nhwc<<<dim3(Kk), 448, 0, stream>>>(nhwc, rois, out);
}

// Round 3
// 104.894 us; speedup vs baseline: 1.5624x; 1.5624x over previous
//
#include <hip/hip_runtime.h>
#include <hip/hip_bf16.h>

// RoIAlign forward, torchvision semantics (aligned=false), fp32 in/out.
// N=2, C=256, H=200, W=200, K=1000 rois, pooled 7x7, sampling_ratio=2.
// Strategy: NCHW f32 -> NHWC bf16 staging map (41 MB, L3-resident), then
// one block per roi gathering 8B/lane (4 bf16 channels) fully coalesced.
constexpr int Nn = 2, Cc = 256, Hh = 200, Ww = 200, Kk = 1000;
constexpr int PH = 7, PW = 7, SR = 2;
constexpr float SCALE = 0.25f;
constexpr int HWsz = Hh * Ww;

// ---------------------------------------------------------------------------
// NCHW fp32 -> NHWC bf16 (RTNE via __float2bfloat16). 64x64 LDS tiles,
// coalesced on both sides.
// ---------------------------------------------------------------------------
__global__ __launch_bounds__(256) void transpose_to_nhwc_bf16(
    const float* __restrict__ in, __hip_bfloat16* __restrict__ out) {
  __shared__ float tile[64][65];
  const int hw0 = blockIdx.x * 64;
  const int c0  = blockIdx.y * 64;
  const int b   = blockIdx.z;
  const int lane = threadIdx.x & 63;
  const int row  = threadIdx.x >> 6;  // 0..3

#pragma unroll
  for (int i = 0; i < 16; ++i) {
    const int cc = row + i * 4;
    tile[cc][lane] = in[(size_t)(b * Cc + c0 + cc) * HWsz + hw0 + lane];
  }
  __syncthreads();
#pragma unroll
  for (int i = 0; i < 16; ++i) {
    const int hh = row + i * 4;
    out[((size_t)b * HWsz + hw0 + hh) * Cc + c0 + lane] =
        __float2bfloat16(tile[lane][hh]);
  }
}

// Skewed LDS stage index: write pattern (c = 4*lane+j) hits bank
// (17*lane + 17*j + p) % 32 -> stride 17, conflict-free. Reads are linear
// + a rare +13 jump: quasi-conflict-free.
__device__ __forceinline__ int sidx(int c, int p) {
  return c * 49 + p + 13 * (c >> 2);
}

// ---------------------------------------------------------------------------
// RoI align on NHWC bf16. One block per roi, 448 threads = 7 waves.
// wave = pooled row ph; lane = 4-channel group (ushort4 = 8B loads; each
// bilinear neighbor gather = contiguous 512B across the wave).
// ---------------------------------------------------------------------------
__global__ __launch_bounds__(448, 7) void roi_align_nhwc_bf16(
    const ushort* __restrict__ feat, const float* __restrict__ rois,
    float* __restrict__ out) {
  __shared__ float stage[6704];  // 128ch phase, skewed: max idx 6674

  const int k    = blockIdx.x;
  const int ph   = (int)(threadIdx.x >> 6);   // 0..6
  const int lane = (int)(threadIdx.x & 63);

  const float* r = rois + k * 5;
  const int b = (int)r[0];
  const float x1 = r[1] * SCALE;
  const float y1 = r[2] * SCALE;
  const float x2 = r[3] * SCALE;
  const float y2 = r[4] * SCALE;
  const float bin_w = fmaxf(x2 - x1, 1.0f) * (1.0f / PW);
  const float bin_h = fmaxf(y2 - y1, 1.0f) * (1.0f / PH);

  // ushort4 view: batch base + lane; index stride per (y,x) position is 64.
  const ushort4* fb =
      (const ushort4*)(feat + (size_t)b * HWsz * Cc) + lane;

  float4 acc[PW];
#pragma unroll
  for (int i = 0; i < PW; ++i) acc[i] = make_float4(0.f, 0.f, 0.f, 0.f);

  auto bf2f = [](ushort u) -> float {
    return __uint_as_float((unsigned)u << 16);
  };

#pragma unroll
  for (int iy = 0; iy < SR; ++iy) {
    const float y  = y1 + ((float)ph + ((float)iy + 0.5f) * 0.5f) * bin_h;
    const bool vy  = (y >= -1.0f) && (y <= (float)Hh);
    const float cy = fmaxf(y, 0.0f);
    int yl = (int)cy;  // cy >= 0: trunc == floor
    int yh;
    float fy;
    if (yl >= Hh - 1) { yl = Hh - 1; yh = Hh - 1; fy = 0.0f; }
    else              { yh = yl + 1; fy = cy - (float)yl; }
    float wyl = 1.0f - fy, wyh = fy;
    if (!vy) { wyl = 0.0f; wyh = 0.0f; }
    const int ylb = yl * Ww, yhb = yh * Ww;

#pragma unroll
    for (int pw = 0; pw < PW; ++pw) {
#pragma unroll
      for (int ix = 0; ix < SR; ++ix) {
        const float x  = x1 + ((float)pw + ((float)ix + 0.5f) * 0.5f) * bin_w;
        const bool vx  = (x >= -1.0f) && (x <= (float)Ww);
        const float cx = fmaxf(x, 0.0f);
        int xl = (int)cx;
        int xh;
        float fx;
        if (xl >= Ww - 1) { xl = Ww - 1; xh = Ww - 1; fx = 0.0f; }
        else              { xh = xl + 1; fx = cx - (float)xl; }
        float wxl = 1.0f - fx, wxh = fx;
        if (!vx) { wxl = 0.0f; wxh = 0.0f; }

        const float w00 = wyl * wxl, w01 = wyl * wxh;
        const float w10 = wyh * wxl, w11 = wyh * wxh;

        const ushort4 v00 = fb[(ylb + xl) * 64];
        const ushort4 v01 = fb[(ylb + xh) * 64];
        const ushort4 v10 = fb[(yhb + xl) * 64];
        const ushort4 v11 = fb[(yhb + xh) * 64];

        acc[pw].x = fmaf(w00, bf2f(v00.x), fmaf(w01, bf2f(v01.x),
                    fmaf(w10, bf2f(v10.x), fmaf(w11, bf2f(v11.x), acc[pw].x))));
        acc[pw].y = fmaf(w00, bf2f(v00.y), fmaf(w01, bf2f(v01.y),
                    fmaf(w10, bf2f(v10.y), fmaf(w11, bf2f(v11.y), acc[pw].y))));
        acc[pw].z = fmaf(w00, bf2f(v00.z), fmaf(w01, bf2f(v01.z),
                    fmaf(w10, bf2f(v10.z), fmaf(w11, bf2f(v11.z), acc[pw].z))));
        acc[pw].w = fmaf(w00, bf2f(v00.w), fmaf(w01, bf2f(v01.w),
                    fmaf(w10, bf2f(v10.w), fmaf(w11, bf2f(v11.w), acc[pw].w))));
      }
    }
  }

  const float inv = 1.0f / (SR * SR);
  const size_t obase = (size_t)k * (Cc * PH * PW);

  // Phase A: channels [0,128).
  if (lane < 32) {
    const int c0 = lane * 4;  // local channel within phase
    const int p = ph * PW;
#pragma unroll
    for (int pw = 0; pw < PW; ++pw) {
      stage[sidx(c0 + 0, p + pw)] = acc[pw].x * inv;
      stage[sidx(c0 + 1, p + pw)] = acc[pw].y * inv;
      stage[sidx(c0 + 2, p + pw)] = acc[pw].z * inv;
      stage[sidx(c0 + 3, p + pw)] = acc[pw].w * inv;
    }
  }
  __syncthreads();
#pragma unroll
  for (int i = 0; i < 14; ++i) {  // 128*49 = 6272 = 448*14
    const int idx = i * 448 + (int)threadIdx.x;
    const int c = idx / 49, p = idx - c * 49;
    out[obase + idx] = stage[sidx(c, p)];
  }
  __syncthreads();

  // Phase B: channels [128,256).
  if (lane >= 32) {
    const int c0 = (lane - 32) * 4;
    const int p = ph * PW;
#pragma unroll
    for (int pw = 0; pw < PW; ++pw) {
      stage[sidx(c0 + 0, p + pw)] = acc[pw].x * inv;
      stage[sidx(c0 + 1, p + pw)] = acc[pw].y * inv;
      stage[sidx(c0 + 2, p + pw)] = acc[pw].z * inv;
      stage[sidx(c0 + 3, p + pw)] = acc[pw].w * inv;
    }
  }
  __syncthreads();
#pragma unroll
  for (int i = 0; i < 14; ++i) {
    const int idx = i * 448 + (int)threadIdx.x;
    const int c = idx / 49, p = idx - c * 49;
    out[obase + 6272 + idx] = stage[sidx(c, p)];
  }
}

extern "C" void kernel_launch(void* const* d_in, const int* in_sizes, int n_in,
                              void* d_out, int out_size, void* d_ws, size_t ws_size,
                              hipStream_t stream) {
  const float* inp  = (const float*)d_in[0];   // (2,256,200,200) fp32
  const float* rois = (const float*)d_in[1];   // (1000,5) fp32
  float* out = (float*)d_out;                  // (1000,256,7,7) fp32

  __hip_bfloat16* nhwc = (__hip_bfloat16*)d_ws;  // 41 MB
  transpose_to_nhwc_bf16<<<dim3(HWsz / 64, Cc / 64, Nn), 256, 0, stream>>>(inp, nhwc);
  roi_align_nhwc_bf16<<<dim3(Kk), 448, 0, stream>>>((const ushort*)nhwc, rois, out);
}

// Round 4
// 72.404 us; speedup vs baseline: 2.2635x; 1.4487x over previous
//
#include <hip/hip_runtime.h>
#include <hip/hip_bf16.h>

// RoIAlign forward, torchvision semantics (aligned=false), fp32 in/out.
// N=2, C=256, H=200, W=200, K=1000 rois, pooled 7x7, sampling_ratio=2.
// Strategy: NCHW f32 -> NHWC bf16 staging map (41 MB, L3-resident), then
// 2 blocks per roi (128-channel halves) gathering 8B/lane; lanes 0-31 and
// 32-63 of each wave handle the two ix sample columns of the same bin
// (folded by shfl_xor(32) at the end).
constexpr int Nn = 2, Cc = 256, Hh = 200, Ww = 200, Kk = 1000;
constexpr int PH = 7, PW = 7, SR = 2;
constexpr float SCALE = 0.25f;
constexpr int HWsz = Hh * Ww;

// ---------------------------------------------------------------------------
// NCHW fp32 -> NHWC bf16 (RTNE). 64x64 LDS tiles, coalesced both sides.
// ---------------------------------------------------------------------------
__global__ __launch_bounds__(256) void transpose_to_nhwc_bf16(
    const float* __restrict__ in, __hip_bfloat16* __restrict__ out) {
  __shared__ float tile[64][65];
  const int hw0 = blockIdx.x * 64;
  const int c0  = blockIdx.y * 64;
  const int b   = blockIdx.z;
  const int lane = threadIdx.x & 63;
  const int row  = threadIdx.x >> 6;  // 0..3

#pragma unroll
  for (int i = 0; i < 16; ++i) {
    const int cc = row + i * 4;
    tile[cc][lane] = in[(size_t)(b * Cc + c0 + cc) * HWsz + hw0 + lane];
  }
  __syncthreads();
#pragma unroll
  for (int i = 0; i < 16; ++i) {
    const int hh = row + i * 4;
    out[((size_t)b * HWsz + hw0 + hh) * Cc + c0 + lane] =
        __float2bfloat16(tile[lane][hh]);
  }
}

// Skewed LDS index: writer lanes (c=4*cq+j) land on bank stride 209%32=17,
// coprime with 32 -> conflict-free writes; reads are quasi-linear.
__device__ __forceinline__ int sidx(int c, int p) {
  return c * 49 + p + 13 * (c >> 2);
}

// ---------------------------------------------------------------------------
// RoI align on NHWC bf16. Grid (K, 2): block = (roi, 128-channel half).
// 448 threads = 7 waves; wave = pooled row ph. Within a wave:
//   ixl = lane>>5  : which of the 2 x-sample columns this lane handles
//   cq  = lane&31  : channel quad within the 128-ch half (8B ushort4 loads)
// Each gather instruction covers 2 sample positions x 256B, fully coalesced.
// ---------------------------------------------------------------------------
__global__ __launch_bounds__(448, 7) void roi_align_nhwc_bf16(
    const ushort* __restrict__ feat, const float* __restrict__ rois,
    float* __restrict__ out) {
  __shared__ float stage[6704];  // 128ch x 49, skewed (max idx 6674)

  const int k    = blockIdx.x;
  const int half = blockIdx.y;                // channel half
  const int ph   = (int)(threadIdx.x >> 6);   // 0..6
  const int lane = (int)(threadIdx.x & 63);
  const int ixl  = lane >> 5;                 // sample column parity
  const int cq   = lane & 31;                 // channel quad in half

  const float* r = rois + k * 5;
  const int b = (int)r[0];
  const float x1 = r[1] * SCALE;
  const float y1 = r[2] * SCALE;
  const float x2 = r[3] * SCALE;
  const float y2 = r[4] * SCALE;
  const float bin_w = fmaxf(x2 - x1, 1.0f) * (1.0f / PW);
  const float bin_h = fmaxf(y2 - y1, 1.0f) * (1.0f / PH);

  // ushort4 view; per-(y,x) stride is 64 quads; this lane's channel quad.
  const ushort4* fb =
      (const ushort4*)(feat + (size_t)b * HWsz * Cc) + half * 32 + cq;

  float4 acc[PW];
#pragma unroll
  for (int i = 0; i < PW; ++i) acc[i] = make_float4(0.f, 0.f, 0.f, 0.f);

  auto bf2f = [](ushort u) -> float {
    return __uint_as_float((unsigned)u << 16);
  };

  const float x_off = ((float)ixl + 0.5f) * 0.5f;  // per-lane sample offset

#pragma unroll
  for (int iy = 0; iy < SR; ++iy) {
    const float y  = y1 + ((float)ph + ((float)iy + 0.5f) * 0.5f) * bin_h;
    const bool vy  = (y >= -1.0f) && (y <= (float)Hh);
    const float cy = fmaxf(y, 0.0f);
    int yl = (int)cy;  // cy >= 0: trunc == floor
    int yh;
    float fy;
    if (yl >= Hh - 1) { yl = Hh - 1; yh = Hh - 1; fy = 0.0f; }
    else              { yh = yl + 1; fy = cy - (float)yl; }
    float wyl = 1.0f - fy, wyh = fy;
    if (!vy) { wyl = 0.0f; wyh = 0.0f; }
    const int ylb = yl * Ww, yhb = yh * Ww;

#pragma unroll
    for (int pw = 0; pw < PW; ++pw) {
      const float x  = x1 + ((float)pw + x_off) * bin_w;  // per-lane
      const bool vx  = (x >= -1.0f) && (x <= (float)Ww);
      const float cx = fmaxf(x, 0.0f);
      int xl = (int)cx;
      int xh;
      float fx;
      if (xl >= Ww - 1) { xl = Ww - 1; xh = Ww - 1; fx = 0.0f; }
      else              { xh = xl + 1; fx = cx - (float)xl; }
      float wxl = 1.0f - fx, wxh = fx;
      if (!vx) { wxl = 0.0f; wxh = 0.0f; }

      const float w00 = wyl * wxl, w01 = wyl * wxh;
      const float w10 = wyh * wxl, w11 = wyh * wxh;

      const ushort4 v00 = fb[(ylb + xl) * 64];
      const ushort4 v01 = fb[(ylb + xh) * 64];
      const ushort4 v10 = fb[(yhb + xl) * 64];
      const ushort4 v11 = fb[(yhb + xh) * 64];

      acc[pw].x = fmaf(w00, bf2f(v00.x), fmaf(w01, bf2f(v01.x),
                  fmaf(w10, bf2f(v10.x), fmaf(w11, bf2f(v11.x), acc[pw].x))));
      acc[pw].y = fmaf(w00, bf2f(v00.y), fmaf(w01, bf2f(v01.y),
                  fmaf(w10, bf2f(v10.y), fmaf(w11, bf2f(v11.y), acc[pw].y))));
      acc[pw].z = fmaf(w00, bf2f(v00.z), fmaf(w01, bf2f(v01.z),
                  fmaf(w10, bf2f(v10.z), fmaf(w11, bf2f(v11.z), acc[pw].z))));
      acc[pw].w = fmaf(w00, bf2f(v00.w), fmaf(w01, bf2f(v01.w),
                  fmaf(w10, bf2f(v10.w), fmaf(w11, bf2f(v11.w), acc[pw].w))));
    }
  }

  // Fold the two x-sample columns: lane L <-> lane L^32.
#pragma unroll
  for (int pw = 0; pw < PW; ++pw) {
    acc[pw].x += __shfl_xor(acc[pw].x, 32);
    acc[pw].y += __shfl_xor(acc[pw].y, 32);
    acc[pw].z += __shfl_xor(acc[pw].z, 32);
    acc[pw].w += __shfl_xor(acc[pw].w, 32);
  }

  const float inv = 1.0f / (SR * SR);
  // Stage this block's 128x49 output tile in LDS (lanes 0-31 hold full sums).
  if (lane < 32) {
    const int c0 = cq * 4;
    const int p = ph * PW;
#pragma unroll
    for (int pw = 0; pw < PW; ++pw) {
      stage[sidx(c0 + 0, p + pw)] = acc[pw].x * inv;
      stage[sidx(c0 + 1, p + pw)] = acc[pw].y * inv;
      stage[sidx(c0 + 2, p + pw)] = acc[pw].z * inv;
      stage[sidx(c0 + 3, p + pw)] = acc[pw].w * inv;
    }
  }
  __syncthreads();

  const size_t obase = (size_t)k * (Cc * PH * PW) + (size_t)half * (128 * PH * PW);
#pragma unroll
  for (int i = 0; i < 14; ++i) {  // 128*49 = 6272 = 448*14
    const int idx = i * 448 + (int)threadIdx.x;
    const int c = idx / 49, p = idx - c * 49;
    out[obase + idx] = stage[sidx(c, p)];
  }
}

extern "C" void kernel_launch(void* const* d_in, const int* in_sizes, int n_in,
                              void* d_out, int out_size, void* d_ws, size_t ws_size,
                              hipStream_t stream) {
  const float* inp  = (const float*)d_in[0];   // (2,256,200,200) fp32
  const float* rois = (const float*)d_in[1];   // (1000,5) fp32
  float* out = (float*)d_out;                  // (1000,256,7,7) fp32

  __hip_bfloat16* nhwc = (__hip_bfloat16*)d_ws;  // 41 MB
  transpose_to_nhwc_bf16<<<dim3(HWsz / 64, Cc / 64, Nn), 256, 0, stream>>>(inp, nhwc);
  roi_align_nhwc_bf16<<<dim3(Kk, 2), 448, 0, stream>>>((const ushort*)nhwc, rois, out);
}

// Round 5
// 70.770 us; speedup vs baseline: 2.3158x; 1.0231x over previous
//
#include <hip/hip_runtime.h>
#include <hip/hip_bf16.h>

// RoIAlign forward, torchvision semantics (aligned=false), fp32 in/out.
// N=2, C=256, H=200, W=200, K=1000 rois, pooled 7x7, sampling_ratio=2.
// Strategy: NCHW f32 -> NHWC bf16 staging map (41 MB, L3-resident), then
// 2 blocks per roi (128-channel halves). Per wave, each iy phase issues all
// 28 gathers (7 pw x 4 bilinear neighbors, 8B/lane) into registers before
// consuming -> ~28 loads in flight per wave (latency hiding via MLP).
constexpr int Nn = 2, Cc = 256, Hh = 200, Ww = 200, Kk = 1000;
constexpr int PH = 7, PW = 7, SR = 2;
constexpr float SCALE = 0.25f;
constexpr int HWsz = Hh * Ww;

// ---------------------------------------------------------------------------
// NCHW fp32 -> NHWC bf16 (RTNE). 64x64 LDS tiles, coalesced both sides.
// ---------------------------------------------------------------------------
__global__ __launch_bounds__(256) void transpose_to_nhwc_bf16(
    const float* __restrict__ in, __hip_bfloat16* __restrict__ out) {
  __shared__ float tile[64][65];
  const int hw0 = blockIdx.x * 64;
  const int c0  = blockIdx.y * 64;
  const int b   = blockIdx.z;
  const int lane = threadIdx.x & 63;
  const int row  = threadIdx.x >> 6;  // 0..3

#pragma unroll
  for (int i = 0; i < 16; ++i) {
    const int cc = row + i * 4;
    tile[cc][lane] = in[(size_t)(b * Cc + c0 + cc) * HWsz + hw0 + lane];
  }
  __syncthreads();
#pragma unroll
  for (int i = 0; i < 16; ++i) {
    const int hh = row + i * 4;
    out[((size_t)b * HWsz + hw0 + hh) * Cc + c0 + lane] =
        __float2bfloat16(tile[lane][hh]);
  }
}

// Skewed LDS index: writer lanes land on bank stride 17 (coprime with 32)
// -> conflict-free writes; reads quasi-linear.
__device__ __forceinline__ int sidx(int c, int p) {
  return c * 49 + p + 13 * (c >> 2);
}

// ---------------------------------------------------------------------------
// RoI align on NHWC bf16. Grid (K, 2): block = (roi, 128-channel half).
// 448 threads = 7 waves; wave = pooled row ph. Within a wave:
//   ixl = lane>>5 : which of the 2 x-sample columns this lane handles
//   cq  = lane&31 : channel quad within the 128-ch half (8B ushort4 loads)
// launch_bounds(448,4): VGPR cap 128 so the 28-gather batch stays in regs.
// ---------------------------------------------------------------------------
__global__ __launch_bounds__(448, 4) void roi_align_nhwc_bf16(
    const ushort* __restrict__ feat, const float* __restrict__ rois,
    float* __restrict__ out) {
  __shared__ float stage[6704];  // 128ch x 49, skewed (max idx 6674)

  const int k    = blockIdx.x;
  const int half = blockIdx.y;                // channel half
  const int ph   = (int)(threadIdx.x >> 6);   // 0..6
  const int lane = (int)(threadIdx.x & 63);
  const int ixl  = lane >> 5;                 // sample column parity
  const int cq   = lane & 31;                 // channel quad in half

  const float* r = rois + k * 5;
  const int b = (int)r[0];
  const float x1 = r[1] * SCALE;
  const float y1 = r[2] * SCALE;
  const float x2 = r[3] * SCALE;
  const float y2 = r[4] * SCALE;
  const float bin_w = fmaxf(x2 - x1, 1.0f) * (1.0f / PW);
  const float bin_h = fmaxf(y2 - y1, 1.0f) * (1.0f / PH);

  // ushort4 view; per-(y,x) stride is 64 quads; this lane's channel quad.
  const ushort4* fb =
      (const ushort4*)(feat + (size_t)b * HWsz * Cc) + half * 32 + cq;

  float4 acc[PW];
#pragma unroll
  for (int i = 0; i < PW; ++i) acc[i] = make_float4(0.f, 0.f, 0.f, 0.f);

  auto bf2f = [](ushort u) -> float {
    return __uint_as_float((unsigned)u << 16);
  };

  const float x_off = ((float)ixl + 0.5f) * 0.5f;  // per-lane sample offset

#pragma unroll
  for (int iy = 0; iy < SR; ++iy) {
    const float y  = y1 + ((float)ph + ((float)iy + 0.5f) * 0.5f) * bin_h;
    const bool vy  = (y >= -1.0f) && (y <= (float)Hh);
    const float cy = fmaxf(y, 0.0f);
    int yl = (int)cy;  // cy >= 0: trunc == floor
    int yh;
    float fy;
    if (yl >= Hh - 1) { yl = Hh - 1; yh = Hh - 1; fy = 0.0f; }
    else              { yh = yl + 1; fy = cy - (float)yl; }
    float wyl = 1.0f - fy, wyh = fy;
    if (!vy) { wyl = 0.0f; wyh = 0.0f; }
    const int ylb = yl * Ww, yhb = yh * Ww;

    // ---- Phase 1: compute addresses, issue all 28 gathers into regs ----
    ushort4 v00[PW], v01[PW], v10[PW], v11[PW];
#pragma unroll
    for (int pw = 0; pw < PW; ++pw) {
      const float x  = x1 + ((float)pw + x_off) * bin_w;  // per-lane
      const float cx = fmaxf(x, 0.0f);
      int xl = (int)cx;
      int xh;
      if (xl >= Ww - 1) { xl = Ww - 1; xh = Ww - 1; }
      else              { xh = xl + 1; }
      v00[pw] = fb[(ylb + xl) * 64];
      v01[pw] = fb[(ylb + xh) * 64];
      v10[pw] = fb[(yhb + xl) * 64];
      v11[pw] = fb[(yhb + xh) * 64];
    }

    // ---- Phase 2: recompute weights (cheap VALU), accumulate ----
#pragma unroll
    for (int pw = 0; pw < PW; ++pw) {
      const float x  = x1 + ((float)pw + x_off) * bin_w;
      const bool vx  = (x >= -1.0f) && (x <= (float)Ww);
      const float cx = fmaxf(x, 0.0f);
      const int xl = (int)cx;
      float fx;
      if (xl >= Ww - 1) { fx = 0.0f; }
      else              { fx = cx - (float)xl; }
      float wxl = 1.0f - fx, wxh = fx;
      if (!vx) { wxl = 0.0f; wxh = 0.0f; }

      const float w00 = wyl * wxl, w01 = wyl * wxh;
      const float w10 = wyh * wxl, w11 = wyh * wxh;

      acc[pw].x = fmaf(w00, bf2f(v00[pw].x), fmaf(w01, bf2f(v01[pw].x),
                  fmaf(w10, bf2f(v10[pw].x), fmaf(w11, bf2f(v11[pw].x), acc[pw].x))));
      acc[pw].y = fmaf(w00, bf2f(v00[pw].y), fmaf(w01, bf2f(v01[pw].y),
                  fmaf(w10, bf2f(v10[pw].y), fmaf(w11, bf2f(v11[pw].y), acc[pw].y))));
      acc[pw].z = fmaf(w00, bf2f(v00[pw].z), fmaf(w01, bf2f(v01[pw].z),
                  fmaf(w10, bf2f(v10[pw].z), fmaf(w11, bf2f(v11[pw].z), acc[pw].z))));
      acc[pw].w = fmaf(w00, bf2f(v00[pw].w), fmaf(w01, bf2f(v01[pw].w),
                  fmaf(w10, bf2f(v10[pw].w), fmaf(w11, bf2f(v11[pw].w), acc[pw].w))));
    }
  }

  // Fold the two x-sample columns: lane L <-> lane L^32.
#pragma unroll
  for (int pw = 0; pw < PW; ++pw) {
    acc[pw].x += __shfl_xor(acc[pw].x, 32);
    acc[pw].y += __shfl_xor(acc[pw].y, 32);
    acc[pw].z += __shfl_xor(acc[pw].z, 32);
    acc[pw].w += __shfl_xor(acc[pw].w, 32);
  }

  const float inv = 1.0f / (SR * SR);
  // Stage this block's 128x49 output tile in LDS (lanes 0-31 hold full sums).
  if (lane < 32) {
    const int c0 = cq * 4;
    const int p = ph * PW;
#pragma unroll
    for (int pw = 0; pw < PW; ++pw) {
      stage[sidx(c0 + 0, p + pw)] = acc[pw].x * inv;
      stage[sidx(c0 + 1, p + pw)] = acc[pw].y * inv;
      stage[sidx(c0 + 2, p + pw)] = acc[pw].z * inv;
      stage[sidx(c0 + 3, p + pw)] = acc[pw].w * inv;
    }
  }
  __syncthreads();

  const size_t obase = (size_t)k * (Cc * PH * PW) + (size_t)half * (128 * PH * PW);
#pragma unroll
  for (int i = 0; i < 14; ++i) {  // 128*49 = 6272 = 448*14
    const int idx = i * 448 + (int)threadIdx.x;
    const int c = idx / 49, p = idx - c * 49;
    out[obase + idx] = stage[sidx(c, p)];
  }
}

extern "C" void kernel_launch(void* const* d_in, const int* in_sizes, int n_in,
                              void* d_out, int out_size, void* d_ws, size_t ws_size,
                              hipStream_t stream) {
  const float* inp  = (const float*)d_in[0];   // (2,256,200,200) fp32
  const float* rois = (const float*)d_in[1];   // (1000,5) fp32
  float* out = (float*)d_out;                  // (1000,256,7,7) fp32

  __hip_bfloat16* nhwc = (__hip_bfloat16*)d_ws;  // 41 MB
  transpose_to_nhwc_bf16<<<dim3(HWsz / 64, Cc / 64, Nn), 256, 0, stream>>>(inp, nhwc);
  roi_align_nhwc_bf16<<<dim3(Kk, 2), 448, 0, stream>>>((const ushort*)nhwc, rois, out);
}